// Round 5
// baseline (34.396 us; speedup 1.0000x reference)
//
#include <hip/hip_runtime.h>
#include <hip/hip_bf16.h>

// SoftToHardQuantize forward == hard quantize (soft path cancels in value).
// R2's exact 16-way scan passed (absmax 0.0) but is VALU-issue-bound
// (~80 slots/elem -> 18.7us; memory floor ~5-10us).
// R5: exact-threshold counting. Prep kernel sorts codes and binary-searches
// (in ordered-float-bit space) the EXACT flip point of the np.argmin pairwise
// predicate for each adjacent sorted pair, including the ==/first-index tie
// rule. Main kernel: idx = #(x >= T_k)  (15 cmp+addc)  ->  sorted[idx] via
// LDS (16 distinct words -> conflict-free; same-address = broadcast).
// Exactness: within [a,b] both rounded distances are monotone in x, so the
// predicate flips once; data range |x|<~6 with code gaps >> ulp(6) rules out
// cross-pair rounding ties. Bit-identical to the 16-way argmin on this data.

#define NCODES 16

typedef float vfloat4 __attribute__((ext_vector_type(4)));

__device__ __forceinline__ unsigned f2o(float f) {
    unsigned u = __float_as_uint(f);
    return (u & 0x80000000u) ? ~u : (u | 0x80000000u);
}
__device__ __forceinline__ float o2f(unsigned o) {
    unsigned u = (o & 0x80000000u) ? (o & 0x7fffffffu) : ~o;
    return __uint_as_float(u);
}

// ws layout: [0..15] sorted codes, [16..30] thresholds
__global__ void stq_prep(const float* __restrict__ C, float* __restrict__ ws, int L) {
    __shared__ float s_val[NCODES];
    __shared__ int   s_idx[NCODES];
    int t = threadIdx.x;

    if (t == 0) {
        float v[NCODES]; int id[NCODES];
        for (int i = 0; i < L; ++i) { v[i] = C[i]; id[i] = i; }
        for (int i = 1; i < L; ++i) {            // stable insertion sort
            float x = v[i]; int xi = id[i]; int j = i - 1;
            while (j >= 0 && v[j] > x) { v[j+1] = v[j]; id[j+1] = id[j]; --j; }
            v[j+1] = x; id[j+1] = xi;
        }
        for (int i = 0; i < L; ++i) { s_val[i] = v[i]; s_idx[i] = id[i]; }
    }
    __syncthreads();

    if (t < L) ws[t] = s_val[t];

    if (t < L - 1) {
        float a = s_val[t], b = s_val[t+1];
        int   ia = s_idx[t], ib = s_idx[t+1];
        float T;
        if (a == b) {
            // duplicate codes: tie everywhere; stable sort => ia<ib => lower always wins
            T = 3.4e38f;
        } else {
            // p(x): upper code wins per np.argmin (strict <, tie -> lower orig idx)
            // p(a)=false, p(b)=true, monotone in [a,b] -> binary search in bit space
            unsigned lo = f2o(a), hi = f2o(b);
            while (hi - lo > 1u) {
                unsigned mid = lo + (hi - lo) / 2u;
                float x  = o2f(mid);
                float da = fabsf(x - a);
                float db = fabsf(x - b);
                bool p = (db < da) || (db == da && ib < ia);
                if (p) hi = mid; else lo = mid;
            }
            T = o2f(hi);   // smallest float with p true: x >= T  =>  upper wins
        }
        ws[NCODES + t] = T;
    }
}

__device__ __forceinline__ int idx1(float x, const float* T) {
    int idx = 0;
#pragma unroll
    for (int k = 0; k < NCODES - 1; ++k) idx += (x >= T[k]) ? 1 : 0;
    return idx;
}

__global__ __launch_bounds__(256) void stq_main(const vfloat4* __restrict__ in,
                                                vfloat4* __restrict__ out,
                                                const float* __restrict__ ws,
                                                int n4,
                                                const float* __restrict__ in_tail,
                                                float* __restrict__ out_tail,
                                                int n_tail) {
    __shared__ float s_sorted[NCODES];

    // uniform -> SGPRs
    float T[NCODES - 1];
#pragma unroll
    for (int k = 0; k < NCODES - 1; ++k) T[k] = ws[NCODES + k];

    if (threadIdx.x < NCODES) s_sorted[threadIdx.x] = ws[threadIdx.x];
    __syncthreads();

    const int stride = gridDim.x * blockDim.x;
    int i = blockIdx.x * blockDim.x + threadIdx.x;

    for (; i + 3 * stride < n4; i += 4 * stride) {
        vfloat4 v0 = in[i];
        vfloat4 v1 = in[i + stride];
        vfloat4 v2 = in[i + 2 * stride];
        vfloat4 v3 = in[i + 3 * stride];

        vfloat4 r0, r1, r2, r3;
        r0.x = s_sorted[idx1(v0.x, T)]; r0.y = s_sorted[idx1(v0.y, T)];
        r0.z = s_sorted[idx1(v0.z, T)]; r0.w = s_sorted[idx1(v0.w, T)];
        r1.x = s_sorted[idx1(v1.x, T)]; r1.y = s_sorted[idx1(v1.y, T)];
        r1.z = s_sorted[idx1(v1.z, T)]; r1.w = s_sorted[idx1(v1.w, T)];
        r2.x = s_sorted[idx1(v2.x, T)]; r2.y = s_sorted[idx1(v2.y, T)];
        r2.z = s_sorted[idx1(v2.z, T)]; r2.w = s_sorted[idx1(v2.w, T)];
        r3.x = s_sorted[idx1(v3.x, T)]; r3.y = s_sorted[idx1(v3.y, T)];
        r3.z = s_sorted[idx1(v3.z, T)]; r3.w = s_sorted[idx1(v3.w, T)];

        __builtin_nontemporal_store(r0, &out[i]);
        __builtin_nontemporal_store(r1, &out[i + stride]);
        __builtin_nontemporal_store(r2, &out[i + 2 * stride]);
        __builtin_nontemporal_store(r3, &out[i + 3 * stride]);
    }
    for (; i < n4; i += stride) {
        vfloat4 v = in[i];
        vfloat4 r;
        r.x = s_sorted[idx1(v.x, T)]; r.y = s_sorted[idx1(v.y, T)];
        r.z = s_sorted[idx1(v.z, T)]; r.w = s_sorted[idx1(v.w, T)];
        __builtin_nontemporal_store(r, &out[i]);
    }

    int t = blockIdx.x * blockDim.x + threadIdx.x;
    if (t < n_tail) {
        out_tail[t] = s_sorted[idx1(in_tail[t], T)];
    }
}

extern "C" void kernel_launch(void* const* d_in, const int* in_sizes, int n_in,
                              void* d_out, int out_size, void* d_ws, size_t ws_size,
                              hipStream_t stream) {
    const float* inp = (const float*)d_in[0];
    const float* C   = (const float*)d_in[1];
    // d_in[2] = sigma: unused (forward value is exactly the hard quantize)
    float* out = (float*)d_out;
    float* ws  = (float*)d_ws;

    const int n = in_sizes[0];
    const int L = in_sizes[1];  // 16

    stq_prep<<<1, 64, 0, stream>>>(C, ws, L);

    const int n4 = n / 4;
    const int n_tail = n - n4 * 4;

    int blocks = (n4 + 255) / 256;
    if (blocks > 2048) blocks = 2048;
    if (blocks < 1) blocks = 1;

    stq_main<<<blocks, 256, 0, stream>>>((const vfloat4*)inp, (vfloat4*)out, ws, n4,
                                         inp + n4 * 4, out + n4 * 4, n_tail);
}